// Round 1
// baseline (1653.589 us; speedup 1.0000x reference)
//
#include <hip/hip_runtime.h>
#include <math.h>

// ---------------- problem constants ----------------
// C=128, H=W=128, PATCH=4, patch grid 32x32 -> NP=1024, corr map 129x129
#define NPF 1024          // number of patches
#define KTOT 2048         // K = C*16
#define HO 129            // output spatial
#define NLPOW 1.4f
#define EPSF 1e-8f

__device__ __forceinline__ float activate(float c) {
    c = fmaxf(c, 0.0f);
    return powf(c, NLPOW);
}

// ---------------- stage 0: relayout desc1 -> A[p][k], k=c*16+a*4+b ----------------
__global__ void build_A(const float* __restrict__ d1, float* __restrict__ A) {
    int idx = blockIdx.x * 256 + threadIdx.x;
    if (idx >= NPF * KTOT) return;
    int p = idx >> 11;
    int k = idx & (KTOT - 1);
    int c = k >> 4, a = (k >> 2) & 3, b = k & 3;
    int i = p >> 5, j = p & 31;
    A[idx] = d1[c * 16384 + (4 * i + a) * 128 + (4 * j + b)];
}

// ---------------- pnorm[p] = sqrt(sum_k A[p][k]^2) ----------------
__global__ void pnorm_k(const float* __restrict__ A, float* __restrict__ pnorm) {
    int p = blockIdx.x;
    int t = threadIdx.x; // 64 threads = 1 wave
    float s = 0.f;
    for (int k = t; k < KTOT; k += 64) {
        float v = A[p * KTOT + k];
        s += v * v;
    }
    #pragma unroll
    for (int off = 32; off > 0; off >>= 1) s += __shfl_down(s, off);
    if (t == 0) pnorm[p] = sqrtf(s);
}

// ---------------- sq[y][x] = sum_c desc2^2 ----------------
__global__ void sq_k(const float* __restrict__ d2, float* __restrict__ sq) {
    int idx = blockIdx.x * 256 + threadIdx.x;
    if (idx >= 16384) return;
    float s = 0.f;
    for (int c = 0; c < 128; ++c) {
        float v = d2[c * 16384 + idx];
        s += v * v;
    }
    sq[idx] = s;
}

// ---------------- wnorm[y][x] = sqrt(4x4 box of sq, pad 2) ----------------
__global__ void wnorm_k(const float* __restrict__ sq, float* __restrict__ wnorm) {
    int idx = blockIdx.x * 256 + threadIdx.x;
    if (idx >= HO * HO) return;
    int y = idx / HO, x = idx % HO;
    float s = 0.f;
    #pragma unroll
    for (int a = 0; a < 4; ++a) {
        int yy = y - 2 + a;
        if ((unsigned)yy >= 128u) continue;
        #pragma unroll
        for (int b = 0; b < 4; ++b) {
            int xx = x - 2 + b;
            if ((unsigned)xx >= 128u) continue;
            s += sq[yy * 128 + xx];
        }
    }
    wnorm[idx] = sqrtf(s);
}

// ---------------- main conv as implicit GEMM (f32 vector FMA) ----------------
// out[p][y][x] = activate( num / (pnorm[p]*wnorm[y][x] + eps) )
// tiles: BM=32 patches, BN = 8 y-rows x 16 x-cols = 128 positions, BK=32
__global__ __launch_bounds__(256) void conv_gemm(
    const float* __restrict__ A,     // [1024][2048]
    const float* __restrict__ d2,    // [128][128][128]
    const float* __restrict__ pnorm, // [1024]
    const float* __restrict__ wnorm, // [129*129]
    float* __restrict__ out)         // [1024][129][129]
{
    __shared__ __align__(16) float Ast[32][36];   // [k][p] transposed, padded
    __shared__ __align__(16) float Bs[32][132];   // [k][n],  padded to 132

    const int bm = blockIdx.x;   // 0..31
    const int by = blockIdx.y;   // 0..16 (8 rows)
    const int bx = blockIdx.z;   // 0..8  (16 cols)
    const int t  = threadIdx.x;

    const int p0 = bm * 32;
    const int y0 = by * 8;
    const int x0 = bx * 16;

    const int mi = (t >> 5) << 2;  // 0..28
    const int ni = (t & 31) << 2;  // 0..124

    float acc[4][4] = {};

    for (int k0 = 0; k0 < KTOT; k0 += 32) {
        // A tile: 32p x 32k, store transposed
        #pragma unroll
        for (int v = 0; v < 4; ++v) {
            int idx = v * 256 + t;
            int r = idx >> 5, c2 = idx & 31;
            Ast[c2][r] = A[(p0 + r) * KTOT + k0 + c2];
        }
        // B tile: 32k x 128n, implicit im2col from desc2
        #pragma unroll
        for (int v = 0; v < 16; ++v) {
            int idx = v * 256 + t;
            int kk = idx >> 7, n = idx & 127;
            int k = k0 + kk;
            int c = k >> 4, a = (k >> 2) & 3, b = k & 3;
            int yy = y0 + (n >> 4) - 2 + a;
            int xx = x0 + (n & 15) - 2 + b;
            float val = 0.f;
            if ((unsigned)yy < 128u && (unsigned)xx < 128u)
                val = d2[c * 16384 + yy * 128 + xx];
            Bs[kk][n] = val;
        }
        __syncthreads();
        #pragma unroll
        for (int kk = 0; kk < 32; ++kk) {
            float4 av = *reinterpret_cast<const float4*>(&Ast[kk][mi]);
            float4 bv = *reinterpret_cast<const float4*>(&Bs[kk][ni]);
            acc[0][0] += av.x * bv.x; acc[0][1] += av.x * bv.y;
            acc[0][2] += av.x * bv.z; acc[0][3] += av.x * bv.w;
            acc[1][0] += av.y * bv.x; acc[1][1] += av.y * bv.y;
            acc[1][2] += av.y * bv.z; acc[1][3] += av.y * bv.w;
            acc[2][0] += av.z * bv.x; acc[2][1] += av.z * bv.y;
            acc[2][2] += av.z * bv.z; acc[2][3] += av.z * bv.w;
            acc[3][0] += av.w * bv.x; acc[3][1] += av.w * bv.y;
            acc[3][2] += av.w * bv.z; acc[3][3] += av.w * bv.w;
        }
        __syncthreads();
    }

    #pragma unroll
    for (int i2 = 0; i2 < 4; ++i2) {
        int p = p0 + mi + i2;
        float pn = pnorm[p];
        #pragma unroll
        for (int j2 = 0; j2 < 4; ++j2) {
            int n = ni + j2;
            int y = y0 + (n >> 4);
            int x = x0 + (n & 15);
            if (y < HO && x < HO) {
                float w = wnorm[y * HO + x];
                float corrv = acc[i2][j2] / (pn * w + EPSF);
                out[p * (HO * HO) + y * HO + x] = activate(corrv);
            }
        }
    }
}

// ---------------- 3x3 stride-2 pad-1 maxpool over last two dims ----------------
__global__ void maxpool_k(const float* __restrict__ in, float* __restrict__ out,
                          int GG, int h, int hp) {
    int idx = blockIdx.x * 256 + threadIdx.x;
    int tot = GG * hp * hp;
    if (idx >= tot) return;
    int s = idx % hp;
    int r = (idx / hp) % hp;
    int g = idx / (hp * hp);
    const float* base = in + (long)g * h * h;
    int y0 = 2 * r - 1, x0 = 2 * s - 1;
    float m = -1e30f;
    #pragma unroll
    for (int dy = 0; dy < 3; ++dy) {
        int y = y0 + dy;
        if ((unsigned)y >= (unsigned)h) continue;
        #pragma unroll
        for (int dx = 0; dx < 3; ++dx) {
            int x = x0 + dx;
            if ((unsigned)x >= (unsigned)h) continue;
            m = fmaxf(m, base[y * h + x]);
        }
    }
    out[idx] = m;
}

// ---------------- sparse_conv_fwd (weights==1, den==4) + activation ----------------
// out[I][J][y][x] = act( 0.25 * sum_{di,dj} pooled[2I+di][2J+dj][y+1-2di][x+1-2dj] )
__global__ void sparse_fwd_k(const float* __restrict__ pooled, float* __restrict__ out,
                             int G2, int h) {
    int idx = blockIdx.x * 256 + threadIdx.x;
    int tot = G2 * G2 * h * h;
    if (idx >= tot) return;
    int x = idx % h;
    int y = (idx / h) % h;
    int J = (idx / (h * h)) % G2;
    int I = idx / (h * h * G2);
    int G = 2 * G2;
    float s = 0.f;
    #pragma unroll
    for (int di = 0; di < 2; ++di) {
        int yy = y + 1 - 2 * di;
        if ((unsigned)yy >= (unsigned)h) continue;
        #pragma unroll
        for (int dj = 0; dj < 2; ++dj) {
            int xx = x + 1 - 2 * dj;
            if ((unsigned)xx >= (unsigned)h) continue;
            s += pooled[((((2 * I + di) * G) + (2 * J + dj)) * (long)h + yy) * h + xx];
        }
    }
    out[idx] = activate(0.25f * s);
}

// ---------------- backward max_unpool step (in-place on lo) ----------------
// lo: (G,G,hl,hl); pooled: (G,G,hp,hp) == maxpool(lo); up: (G/2,G/2,hp,hp)
__global__ void unpool_k(float* __restrict__ lo, const float* __restrict__ pooled,
                         const float* __restrict__ up, int G, int hl, int hp) {
    int idx = blockIdx.x * 256 + threadIdx.x;
    int tot = G * G * hl * hl;
    if (idx >= tot) return;
    int x = idx % hl;
    int y = (idx / hl) % hl;
    int gj = (idx / (hl * hl)) % G;
    int gi = idx / (hl * hl * G);
    float l = lo[idx];
    float m = pooled[(((long)gi * G + gj) * hp + (y >> 1)) * hp + (x >> 1)];
    if (l == m) {
        int ry = (y >> 1) - 1 + 2 * (gi & 1);
        int rx = (x >> 1) - 1 + 2 * (gj & 1);
        float uv = 0.f;
        if ((unsigned)ry < (unsigned)hp && (unsigned)rx < (unsigned)hp)
            uv = up[((((long)(gi >> 1)) * (G >> 1) + (gj >> 1)) * hp + ry) * hp + rx];
        lo[idx] = fmaxf(l, uv);
    }
}

// ---------------- workspace layout (in floats) ----------------
#define A_OFF     0L
#define PN_OFF    2097152L
#define WN_OFF    2098176L
#define SQ_OFF    2114880L
#define PYR1_OFF  2131264L   // 16x16x65x65   = 1,081,600
#define POOL1_OFF 3212864L   // 32x32x65x65   = 4,326,400
#define PYR2_OFF  7539264L   // 8x8x33x33     = 69,696
#define POOL2_OFF 7608960L   // 16x16x33x33   = 278,784
#define PYR3_OFF  7887744L   // 4x4x17x17     = 4,624
#define POOL3_OFF 7892416L   // 8x8x17x17     = 18,496
#define PYR4_OFF  7910912L   // 2x2x9x9       = 324
#define POOL4_OFF 7911296L   // 4x4x9x9       = 1,296
#define PYR5_OFF  7912640L   // 1x1x5x5       = 25
#define POOL5_OFF 7912704L   // 2x2x5x5       = 100

extern "C" void kernel_launch(void* const* d_in, const int* in_sizes, int n_in,
                              void* d_out, int out_size, void* d_ws, size_t ws_size,
                              hipStream_t stream) {
    const float* d1 = (const float*)d_in[0];
    const float* d2 = (const float*)d_in[1];
    float* out = (float*)d_out;
    float* ws = (float*)d_ws;

    float* A     = ws + A_OFF;
    float* pn    = ws + PN_OFF;
    float* wn    = ws + WN_OFF;
    float* sq    = ws + SQ_OFF;
    float* pyr1  = ws + PYR1_OFF;
    float* pool1 = ws + POOL1_OFF;
    float* pyr2  = ws + PYR2_OFF;
    float* pool2 = ws + POOL2_OFF;
    float* pyr3  = ws + PYR3_OFF;
    float* pool3 = ws + POOL3_OFF;
    float* pyr4  = ws + PYR4_OFF;
    float* pool4 = ws + POOL4_OFF;
    float* pyr5  = ws + PYR5_OFF;
    float* pool5 = ws + POOL5_OFF;

    // stage 0/1: prep
    build_A<<<(NPF * KTOT + 255) / 256, 256, 0, stream>>>(d1, A);
    pnorm_k<<<NPF, 64, 0, stream>>>(A, pn);
    sq_k<<<64, 256, 0, stream>>>(d2, sq);
    wnorm_k<<<(HO * HO + 255) / 256, 256, 0, stream>>>(sq, wn);

    // stage 2: correlation GEMM + normalize + activation -> pyramid0 in d_out
    conv_gemm<<<dim3(32, 17, 9), 256, 0, stream>>>(A, d2, pn, wn, out);

    // forward pyramid (cache pooled at every level)
    maxpool_k<<<(1024 * 65 * 65 + 255) / 256, 256, 0, stream>>>(out, pool1, 1024, 129, 65);
    sparse_fwd_k<<<(256 * 65 * 65 + 255) / 256, 256, 0, stream>>>(pool1, pyr1, 16, 65);

    maxpool_k<<<(256 * 33 * 33 + 255) / 256, 256, 0, stream>>>(pyr1, pool2, 256, 65, 33);
    sparse_fwd_k<<<(64 * 33 * 33 + 255) / 256, 256, 0, stream>>>(pool2, pyr2, 8, 33);

    maxpool_k<<<(64 * 17 * 17 + 255) / 256, 256, 0, stream>>>(pyr2, pool3, 64, 33, 17);
    sparse_fwd_k<<<(16 * 17 * 17 + 255) / 256, 256, 0, stream>>>(pool3, pyr3, 4, 17);

    maxpool_k<<<(16 * 9 * 9 + 255) / 256, 256, 0, stream>>>(pyr3, pool4, 16, 17, 9);
    sparse_fwd_k<<<(4 * 9 * 9 + 255) / 256, 256, 0, stream>>>(pool4, pyr4, 2, 9);

    maxpool_k<<<1, 256, 0, stream>>>(pyr4, pool5, 4, 9, 5);
    sparse_fwd_k<<<1, 256, 0, stream>>>(pool5, pyr5, 1, 5);

    // backward unpool chain (top -> bottom), each updates lo in place
    unpool_k<<<(4 * 81 + 255) / 256, 256, 0, stream>>>(pyr4, pool5, pyr5, 2, 9, 5);
    unpool_k<<<(16 * 289 + 255) / 256, 256, 0, stream>>>(pyr3, pool4, pyr4, 4, 17, 9);
    unpool_k<<<(64 * 1089 + 255) / 256, 256, 0, stream>>>(pyr2, pool3, pyr3, 8, 33, 17);
    unpool_k<<<(256 * 4225 + 255) / 256, 256, 0, stream>>>(pyr1, pool2, pyr2, 16, 65, 33);
    unpool_k<<<(1024 * 16641 + 255) / 256, 256, 0, stream>>>(out, pool1, pyr1, 32, 129, 65);
}

// Round 3
// 1125.845 us; speedup vs baseline: 1.4688x; 1.4688x over previous
//
#include <hip/hip_runtime.h>
#include <hip/hip_fp16.h>
#include <math.h>

typedef unsigned int uint;
typedef unsigned short ushort;
typedef short f16x8 __attribute__((ext_vector_type(8)));
typedef float f32x4 __attribute__((ext_vector_type(4)));

#define NLPOW 1.4f
#define EPSF 1e-8f
#define HO 129

__device__ __forceinline__ float activate(float c) {
    c = fmaxf(c, 0.0f);
    return powf(c, NLPOW);
}

// f16 split with scaled residual: v ~= h + l/2048, h,l are f16 bit patterns.
__device__ __forceinline__ void f16split(float v, ushort& h, ushort& l) {
    __half hv = __float2half(v);           // RNE
    h = __half_as_ushort(hv);
    float r = (v - __half2float(hv)) * 2048.0f;
    l = __half_as_ushort(__float2half(r));
}

// ---------------- prep: padded f16-split of desc2 ----------------
// layout: [128 c][140 y (y+2)][152 x (x+2)] zero-padded outside [0,128)
__global__ void split_d2(const float* __restrict__ d2,
                         ushort* __restrict__ dh, ushort* __restrict__ dl) {
    int idx = blockIdx.x * 256 + threadIdx.x;
    if (idx >= 128 * 140 * 152) return;
    int xp = idx % 152;
    int yp = (idx / 152) % 140;
    int c = idx / 21280;
    int y = yp - 2, x = xp - 2;
    float v = 0.f;
    if ((unsigned)y < 128u && (unsigned)x < 128u)
        v = d2[c * 16384 + y * 128 + x];
    ushort h, lo;
    f16split(v, h, lo);
    dh[idx] = h;
    dl[idx] = lo;
}

// ---------------- prep: A in MFMA-ready LDS-image layout ----------------
// Ag[mb][s][hl][128 rows][40] ushort; k' = s*32+kk, k' = (a*4+b)*128 + c
__global__ void build_Afrag(const float* __restrict__ d1, ushort* __restrict__ Ag) {
    int idx = blockIdx.x * 256 + threadIdx.x;
    if (idx >= 8 * 64 * 128 * 40) return;
    int kk = idx % 40;
    int row = (idx / 40) % 128;
    int s = (idx / 5120) % 64;
    int mb = idx / 327680;
    ushort h = 0, lo = 0;
    if (kk < 32) {
        int kp = s * 32 + kk;
        int c = kp & 127;
        int ab = kp >> 7;
        int a = ab >> 2, b = ab & 3;
        int p = mb * 128 + row;
        int i = p >> 5, j = p & 31;
        float v = d1[c * 16384 + (4 * i + a) * 128 + (4 * j + b)];
        f16split(v, h, lo);
    }
    long o = (long)(mb * 64 + s) * 10240 + row * 40 + kk;
    Ag[o] = h;
    Ag[o + 5120] = lo;
}

// ---------------- pnorm[p] from d1 directly ----------------
__global__ void pnorm_k(const float* __restrict__ d1, float* __restrict__ pn) {
    int p = blockIdx.x;
    int t = threadIdx.x;
    int i = p >> 5, j = p & 31;
    int pix = t & 15;
    int a = pix >> 2, b = pix & 3;
    int cg = t >> 4;
    const float* base = d1 + (4 * i + a) * 128 + (4 * j + b);
    float s = 0.f;
    for (int c = cg * 32; c < cg * 32 + 32; ++c) {
        float v = base[c * 16384];
        s += v * v;
    }
    #pragma unroll
    for (int off = 32; off > 0; off >>= 1) s += __shfl_down(s, off);
    if (t == 0) pn[p] = sqrtf(s);
}

// ---------------- sq[y][x] = sum_c desc2^2 ----------------
__global__ void sq_k(const float* __restrict__ d2, float* __restrict__ sq) {
    int idx = blockIdx.x * 256 + threadIdx.x;
    if (idx >= 16384) return;
    float s = 0.f;
    for (int c = 0; c < 128; ++c) {
        float v = d2[c * 16384 + idx];
        s += v * v;
    }
    sq[idx] = s;
}

// ---------------- wnorm ----------------
__global__ void wnorm_k(const float* __restrict__ sq, float* __restrict__ wnorm) {
    int idx = blockIdx.x * 256 + threadIdx.x;
    if (idx >= HO * HO) return;
    int y = idx / HO, x = idx % HO;
    float s = 0.f;
    #pragma unroll
    for (int a = 0; a < 4; ++a) {
        int yy = y - 2 + a;
        if ((unsigned)yy >= 128u) continue;
        #pragma unroll
        for (int b = 0; b < 4; ++b) {
            int xx = x - 2 + b;
            if ((unsigned)xx >= 128u) continue;
            s += sq[yy * 128 + xx];
        }
    }
    wnorm[idx] = sqrtf(s);
}

// ---------------- main correlation as f16-split MFMA implicit GEMM ----------------
// M=1024 patches, N=129x129 positions (tiled 8y x 16x), K=2048
// corr = accH + accX/2048; LDS = 81920 B -> 2 blocks/CU.
__global__ __launch_bounds__(256, 2) void conv_mfma(
    const ushort* __restrict__ Ag,
    const ushort* __restrict__ d2h, const ushort* __restrict__ d2l,
    const float* __restrict__ pn, const float* __restrict__ wnorm,
    float* __restrict__ out)
{
    __shared__ __align__(16) ushort A2[2][2][5120];
    __shared__ __align__(16) ushort B2[2][2][5120];

    const int t = threadIdx.x;
    const int mb = blockIdx.x / 153;
    const int nb = blockIdx.x % 153;
    const int ny0 = (nb / 9) * 8;
    const int nx0 = (nb % 9) * 16;
    const int p0 = mb * 128;

    const int l = t & 63;
    const int w = t >> 6;
    const int wm = w & 1, wn_ = w >> 1;
    const int lm = l & 15, lg = l >> 4;

    // B staging mapping: m2 = channel pair, chunk -> (ny, nx8)
    const int m2 = t & 15;
    const int chunk = t >> 4;
    const int sny = chunk >> 1;
    const int snx = (chunk & 1) * 8;

    f32x4 accH[4][4] = {};
    f32x4 accX[4][4] = {};

    const long aBase = (long)mb * 64 * 10240;
    uint4 ar[5];
    uint4 Wb[4];
    uint We[4];

    auto loadA = [&](int s) {
        const ushort* src = Ag + aBase + (long)s * 10240;
        #pragma unroll
        for (int i = 0; i < 5; ++i)
            ar[i] = *(const uint4*)(src + (i * 256 + t) * 8);
    };
    auto writeA = [&](int cur) {
        ushort* dst = &A2[cur][0][0];
        #pragma unroll
        for (int i = 0; i < 5; ++i)
            *(uint4*)(dst + (i * 256 + t) * 8) = ar[i];
    };
    auto loadB = [&](int s) {
        int ab = s >> 2;
        int a = ab >> 2, b = ab & 3, c0 = (s & 3) * 32;
        int c = c0 + 2 * m2;
        int yy = ny0 + sny + a - 2;
        int xb = nx0 + snx + b - 2;
        int xa = xb & ~1;
        long base = ((long)(c * 140 + yy + 2)) * 152 + (xa + 2);
        const ushort* q0 = d2h + base;
        const ushort* q2 = d2l + base;
        Wb[0] = *(const uint4*)q0;           We[0] = *(const uint*)(q0 + 8);
        Wb[1] = *(const uint4*)(q0 + 21280); We[1] = *(const uint*)(q0 + 21288);
        Wb[2] = *(const uint4*)q2;           We[2] = *(const uint*)(q2 + 8);
        Wb[3] = *(const uint4*)(q2 + 21280); We[3] = *(const uint*)(q2 + 21288);
    };
    auto writeB = [&](int cur, int s) {
        uint off = ((uint)(s >> 2) & 1u) * 16u;   // = (b&1)*16
        #pragma unroll
        for (int hl = 0; hl < 2; ++hl) {
            uint aa[4], bb[4];
            aa[0] = __builtin_amdgcn_alignbit(Wb[hl*2+0].y, Wb[hl*2+0].x, off);
            aa[1] = __builtin_amdgcn_alignbit(Wb[hl*2+0].z, Wb[hl*2+0].y, off);
            aa[2] = __builtin_amdgcn_alignbit(Wb[hl*2+0].w, Wb[hl*2+0].z, off);
            aa[3] = __builtin_amdgcn_alignbit(We[hl*2+0],   Wb[hl*2+0].w, off);
            bb[0] = __builtin_amdgcn_alignbit(Wb[hl*2+1].y, Wb[hl*2+1].x, off);
            bb[1] = __builtin_amdgcn_alignbit(Wb[hl*2+1].z, Wb[hl*2+1].y, off);
            bb[2] = __builtin_amdgcn_alignbit(Wb[hl*2+1].w, Wb[hl*2+1].z, off);
            bb[3] = __builtin_amdgcn_alignbit(We[hl*2+1],   Wb[hl*2+1].w, off);
            ushort* dst = &B2[cur][hl][0] + 2 * m2;
            #pragma unroll
            for (int i2 = 0; i2 < 4; ++i2) {
                uint lo16 = __builtin_amdgcn_perm(bb[i2], aa[i2], 0x05040100u);
                uint hi16 = __builtin_amdgcn_perm(bb[i2], aa[i2], 0x07060302u);
                *(uint*)(dst + (chunk * 8 + 2 * i2) * 40) = lo16;
                *(uint*)(dst + (chunk * 8 + 2 * i2 + 1) * 40) = hi16;
            }
        }
    };

    // prologue: stage step 0
    loadA(0); loadB(0);
    writeA(0); writeB(0, 0);
    __syncthreads();

    for (int s = 0; s < 64; ++s) {
        const int cur = s & 1;
        if (s < 63) { loadA(s + 1); loadB(s + 1); }   // global loads overlap MFMA

        f16x8 fah[4], fal[4];
        #pragma unroll
        for (int mi = 0; mi < 4; ++mi) {
            int ra = (wm * 64 + mi * 16 + lm) * 40 + lg * 8;
            fah[mi] = *(const f16x8*)(&A2[cur][0][0] + ra);
            fal[mi] = *(const f16x8*)(&A2[cur][1][0] + ra);
        }
        #pragma unroll
        for (int ni = 0; ni < 4; ++ni) {
            int rb = (wn_ * 64 + ni * 16 + lm) * 40 + lg * 8;
            f16x8 fbh = *(const f16x8*)(&B2[cur][0][0] + rb);
            f16x8 fbl = *(const f16x8*)(&B2[cur][1][0] + rb);
            #pragma unroll
            for (int mi = 0; mi < 4; ++mi) {
                accH[mi][ni] = __builtin_amdgcn_mfma_f32_16x16x32_f16(fah[mi], fbh, accH[mi][ni], 0, 0, 0);
                accX[mi][ni] = __builtin_amdgcn_mfma_f32_16x16x32_f16(fah[mi], fbl, accX[mi][ni], 0, 0, 0);
                accX[mi][ni] = __builtin_amdgcn_mfma_f32_16x16x32_f16(fal[mi], fbh, accX[mi][ni], 0, 0, 0);
            }
        }
        __syncthreads();            // all reads of cur done
        if (s < 63) { writeA(cur ^ 1); writeB(cur ^ 1, s + 1); }
        __syncthreads();            // staging visible
    }

    // epilogue: combine, normalize, activate, store
    #pragma unroll
    for (int mi = 0; mi < 4; ++mi) {
        #pragma unroll
        for (int ni = 0; ni < 4; ++ni) {
            int y = ny0 + wn_ * 4 + ni;
            int x = nx0 + lm;
            if (y < HO && x < HO) {
                float wv = wnorm[y * HO + x];
                f32x4 vh = accH[mi][ni];
                f32x4 vx = accX[mi][ni];
                #pragma unroll
                for (int r = 0; r < 4; ++r) {
                    int p = p0 + wm * 64 + mi * 16 + lg * 4 + r;
                    float num = vh[r] + vx[r] * (1.0f / 2048.0f);
                    float c = num / (pn[p] * wv + EPSF);
                    out[(long)p * (HO * HO) + y * HO + x] = activate(c);
                }
            }
        }
    }
}

// ---------------- 3x3 stride-2 pad-1 maxpool ----------------
__global__ void maxpool_k(const float* __restrict__ in, float* __restrict__ out,
                          int GG, int h, int hp) {
    int idx = blockIdx.x * 256 + threadIdx.x;
    int tot = GG * hp * hp;
    if (idx >= tot) return;
    int s = idx % hp;
    int r = (idx / hp) % hp;
    int g = idx / (hp * hp);
    const float* base = in + (long)g * h * h;
    int y0 = 2 * r - 1, x0 = 2 * s - 1;
    float m = -1e30f;
    #pragma unroll
    for (int dy = 0; dy < 3; ++dy) {
        int y = y0 + dy;
        if ((unsigned)y >= (unsigned)h) continue;
        #pragma unroll
        for (int dx = 0; dx < 3; ++dx) {
            int x = x0 + dx;
            if ((unsigned)x >= (unsigned)h) continue;
            m = fmaxf(m, base[y * h + x]);
        }
    }
    out[idx] = m;
}

// ---------------- sparse_conv_fwd (weights==1, den==4) + activation ----------------
__global__ void sparse_fwd_k(const float* __restrict__ pooled, float* __restrict__ out,
                             int G2, int h) {
    int idx = blockIdx.x * 256 + threadIdx.x;
    int tot = G2 * G2 * h * h;
    if (idx >= tot) return;
    int x = idx % h;
    int y = (idx / h) % h;
    int J = (idx / (h * h)) % G2;
    int I = idx / (h * h * G2);
    int G = 2 * G2;
    float s = 0.f;
    #pragma unroll
    for (int di = 0; di < 2; ++di) {
        int yy = y + 1 - 2 * di;
        if ((unsigned)yy >= (unsigned)h) continue;
        #pragma unroll
        for (int dj = 0; dj < 2; ++dj) {
            int xx = x + 1 - 2 * dj;
            if ((unsigned)xx >= (unsigned)h) continue;
            s += pooled[((((2 * I + di) * G) + (2 * J + dj)) * (long)h + yy) * h + xx];
        }
    }
    out[idx] = activate(0.25f * s);
}

// ---------------- backward max_unpool (in place on lo) ----------------
__global__ void unpool_k(float* __restrict__ lo, const float* __restrict__ pooled,
                         const float* __restrict__ up, int G, int hl, int hp) {
    int idx = blockIdx.x * 256 + threadIdx.x;
    int tot = G * G * hl * hl;
    if (idx >= tot) return;
    int x = idx % hl;
    int y = (idx / hl) % hl;
    int gj = (idx / (hl * hl)) % G;
    int gi = idx / (hl * hl * G);
    float l = lo[idx];
    float m = pooled[(((long)gi * G + gj) * hp + (y >> 1)) * hp + (x >> 1)];
    if (l == m) {
        int ry = (y >> 1) - 1 + 2 * (gi & 1);
        int rx = (x >> 1) - 1 + 2 * (gj & 1);
        float uv = 0.f;
        if ((unsigned)ry < (unsigned)hp && (unsigned)rx < (unsigned)hp)
            uv = up[((((long)(gi >> 1)) * (G >> 1) + (gj >> 1)) * hp + ry) * hp + rx];
        lo[idx] = fmaxf(l, uv);
    }
}

// ---------------- workspace layout (floats) — triple-checked ----------------
// d2h plane: 128*140*152 = 2,723,840 ushorts = 1,361,920 floats
// Ag: 8*64*10240 = 5,242,880 ushorts = 2,621,440 floats
#define PN_OFF    0L
#define WN_OFF    1024L                    // 16,641 -> ends 17,665
#define SQ_OFF    17728L                   // 16,384 -> ends 34,112
#define CBASE     34112L
#define D2H_OFF   (CBASE)                  // [CBASE, CBASE+1,361,920)
#define D2L_OFF   (CBASE + 1361920L)       // [.., CBASE+2,723,840)
#define AG_OFF    (CBASE + 2723840L)       // [.., CBASE+5,345,280)
// pyramid phase (disjoint in time from conv-phase buffers above):
#define POOL1_OFF (CBASE)                  // 4,326,400
#define PYR1_OFF  (CBASE + 4326400L)       // 1,081,600
#define POOL2_OFF (CBASE + 5408000L)       // 278,784
#define PYR2_OFF  (CBASE + 5686784L)       // 69,696
#define POOL3_OFF (CBASE + 5756480L)       // 18,496
#define PYR3_OFF  (CBASE + 5774976L)       // 4,624
#define POOL4_OFF (CBASE + 5779600L)       // 1,296
#define PYR4_OFF  (CBASE + 5780896L)       // 324
#define POOL5_OFF (CBASE + 5781220L)       // 100
#define PYR5_OFF  (CBASE + 5781320L)       // 25 -> ends CBASE+5,781,345

extern "C" void kernel_launch(void* const* d_in, const int* in_sizes, int n_in,
                              void* d_out, int out_size, void* d_ws, size_t ws_size,
                              hipStream_t stream) {
    const float* d1 = (const float*)d_in[0];
    const float* d2 = (const float*)d_in[1];
    float* out = (float*)d_out;
    float* ws = (float*)d_ws;

    float* pnf   = ws + PN_OFF;
    float* wnf   = ws + WN_OFF;
    float* sqf   = ws + SQ_OFF;
    ushort* d2h  = (ushort*)(ws + D2H_OFF);
    ushort* d2l  = (ushort*)(ws + D2L_OFF);
    ushort* Ag   = (ushort*)(ws + AG_OFF);
    float* pool1 = ws + POOL1_OFF;
    float* pyr1  = ws + PYR1_OFF;
    float* pool2 = ws + POOL2_OFF;
    float* pyr2  = ws + PYR2_OFF;
    float* pool3 = ws + POOL3_OFF;
    float* pyr3  = ws + PYR3_OFF;
    float* pool4 = ws + POOL4_OFF;
    float* pyr4  = ws + PYR4_OFF;
    float* pool5 = ws + POOL5_OFF;
    float* pyr5  = ws + PYR5_OFF;

    // prep
    split_d2<<<10640, 256, 0, stream>>>(d2, d2h, d2l);
    build_Afrag<<<10240, 256, 0, stream>>>(d1, Ag);
    pnorm_k<<<1024, 64, 0, stream>>>(d1, pnf);
    sq_k<<<64, 256, 0, stream>>>(d2, sqf);
    wnorm_k<<<(HO * HO + 255) / 256, 256, 0, stream>>>(sqf, wnf);

    // correlation GEMM (MFMA) + normalize + activation -> pyramid0 in d_out
    conv_mfma<<<8 * 153, 256, 0, stream>>>(Ag, d2h, d2l, pnf, wnf, out);

    // forward pyramid (cache pooled at every level)
    maxpool_k<<<(1024 * 65 * 65 + 255) / 256, 256, 0, stream>>>(out, pool1, 1024, 129, 65);
    sparse_fwd_k<<<(256 * 65 * 65 + 255) / 256, 256, 0, stream>>>(pool1, pyr1, 16, 65);

    maxpool_k<<<(256 * 33 * 33 + 255) / 256, 256, 0, stream>>>(pyr1, pool2, 256, 65, 33);
    sparse_fwd_k<<<(64 * 33 * 33 + 255) / 256, 256, 0, stream>>>(pool2, pyr2, 8, 33);

    maxpool_k<<<(64 * 17 * 17 + 255) / 256, 256, 0, stream>>>(pyr2, pool3, 64, 33, 17);
    sparse_fwd_k<<<(16 * 17 * 17 + 255) / 256, 256, 0, stream>>>(pool3, pyr3, 4, 17);

    maxpool_k<<<(16 * 9 * 9 + 255) / 256, 256, 0, stream>>>(pyr3, pool4, 16, 17, 9);
    sparse_fwd_k<<<(4 * 9 * 9 + 255) / 256, 256, 0, stream>>>(pool4, pyr4, 2, 9);

    maxpool_k<<<1, 256, 0, stream>>>(pyr4, pool5, 4, 9, 5);
    sparse_fwd_k<<<1, 256, 0, stream>>>(pool5, pyr5, 1, 5);

    // backward unpool chain (top -> bottom), each updates lo in place
    unpool_k<<<(4 * 81 + 255) / 256, 256, 0, stream>>>(pyr4, pool5, pyr5, 2, 9, 5);
    unpool_k<<<(16 * 289 + 255) / 256, 256, 0, stream>>>(pyr3, pool4, pyr4, 4, 17, 9);
    unpool_k<<<(64 * 1089 + 255) / 256, 256, 0, stream>>>(pyr2, pool3, pyr3, 8, 33, 17);
    unpool_k<<<(256 * 4225 + 255) / 256, 256, 0, stream>>>(pyr1, pool2, pyr2, 16, 65, 33);
    unpool_k<<<(1024 * 16641 + 255) / 256, 256, 0, stream>>>(out, pool1, pyr1, 32, 129, 65);
}

// Round 4
// 585.736 us; speedup vs baseline: 2.8231x; 1.9221x over previous
//
#include <hip/hip_runtime.h>
#include <hip/hip_fp16.h>
#include <math.h>

typedef unsigned int uint;
typedef unsigned short ushort;
typedef short f16x8 __attribute__((ext_vector_type(8)));
typedef short f16x4 __attribute__((ext_vector_type(4)));
typedef float f32x4 __attribute__((ext_vector_type(4)));

#define NLPOW 1.4f
#define EPSF 1e-8f
#define HO 129

__device__ __forceinline__ float activate(float c) {
    c = fmaxf(c, 0.0f);
    return powf(c, NLPOW);
}

// f16 split with scaled residual: v ~= h + l/2048 (h,l = f16 bit patterns)
__device__ __forceinline__ void f16split(float v, ushort& h, ushort& l) {
    __half hv = __float2half(v);           // RNE
    h = __half_as_ushort(hv);
    float r = (v - __half2float(hv)) * 2048.0f;
    l = __half_as_ushort(__float2half(r));
}

__device__ __forceinline__ void gld_lds16(const ushort* g, ushort* l) {
    __builtin_amdgcn_global_load_lds(
        (const __attribute__((address_space(1))) void*)g,
        (__attribute__((address_space(3))) void*)l,
        16, 0, 0);
}

// ---------------- prep: padded interleaved f16-split of desc2 ----------------
// d2hl[c][yp][xp] = uint{ h (low16), l (high16) }; [128][140][152], pad 2 each side
__global__ void split_d2(const float* __restrict__ d2, uint* __restrict__ dhl) {
    int idx = blockIdx.x * 256 + threadIdx.x;
    if (idx >= 128 * 140 * 152) return;
    int xp = idx % 152;
    int yp = (idx / 152) % 140;
    int c = idx / 21280;
    int y = yp - 2, x = xp - 2;
    float v = 0.f;
    if ((unsigned)y < 128u && (unsigned)x < 128u)
        v = d2[c * 16384 + y * 128 + x];
    ushort h, lo;
    f16split(v, h, lo);
    dhl[idx] = (uint)h | ((uint)lo << 16);
}

// ---------------- prep: A in linear LDS-image layout ----------------
// Ag[mb][s][hl][128 rows][32 kk] ushort;  k' = s*32+kk = (a*4+b)*128 + c
__global__ void build_Afrag(const float* __restrict__ d1, ushort* __restrict__ Ag) {
    int idx = blockIdx.x * 256 + threadIdx.x;
    if (idx >= 8 * 64 * 128 * 32) return;
    int kk = idx & 31;
    int row = (idx >> 5) & 127;
    int s = (idx >> 12) & 63;
    int mb = idx >> 18;
    int kp = s * 32 + kk;
    int c = kp & 127;
    int ab = kp >> 7;
    int a = ab >> 2, b = ab & 3;
    int p = mb * 128 + row;
    int i = p >> 5, j = p & 31;
    float v = d1[c * 16384 + (4 * i + a) * 128 + (4 * j + b)];
    ushort h, lo;
    f16split(v, h, lo);
    long o = ((long)(mb * 64 + s) * 2) * 4096 + row * 32 + kk;
    Ag[o] = h;
    Ag[o + 4096] = lo;
}

// ---------------- pnorm[p] from d1 directly ----------------
__global__ void pnorm_k(const float* __restrict__ d1, float* __restrict__ pn) {
    int p = blockIdx.x;
    int t = threadIdx.x;
    int i = p >> 5, j = p & 31;
    int pix = t & 15;
    int a = pix >> 2, b = pix & 3;
    int cg = t >> 4;
    const float* base = d1 + (4 * i + a) * 128 + (4 * j + b);
    float s = 0.f;
    for (int c = cg * 32; c < cg * 32 + 32; ++c) {
        float v = base[c * 16384];
        s += v * v;
    }
    #pragma unroll
    for (int off = 32; off > 0; off >>= 1) s += __shfl_down(s, off);
    if (t == 0) pn[p] = sqrtf(s);
}

// ---------------- sq[y][x] = sum_c desc2^2 ----------------
__global__ void sq_k(const float* __restrict__ d2, float* __restrict__ sq) {
    int idx = blockIdx.x * 256 + threadIdx.x;
    if (idx >= 16384) return;
    float s = 0.f;
    for (int c = 0; c < 128; ++c) {
        float v = d2[c * 16384 + idx];
        s += v * v;
    }
    sq[idx] = s;
}

// ---------------- wnorm ----------------
__global__ void wnorm_k(const float* __restrict__ sq, float* __restrict__ wnorm) {
    int idx = blockIdx.x * 256 + threadIdx.x;
    if (idx >= HO * HO) return;
    int y = idx / HO, x = idx % HO;
    float s = 0.f;
    #pragma unroll
    for (int a = 0; a < 4; ++a) {
        int yy = y - 2 + a;
        if ((unsigned)yy >= 128u) continue;
        #pragma unroll
        for (int b = 0; b < 4; ++b) {
            int xx = x - 2 + b;
            if ((unsigned)xx >= 128u) continue;
            s += sq[yy * 128 + xx];
        }
    }
    wnorm[idx] = sqrtf(s);
}

// ---------------- main correlation: f16-split MFMA implicit GEMM ----------------
// M=1024, N=129x129 (tiled 8y x 16x), K=2048. corr = accH + accX/2048.
// XCD-pinned: mb = blockIdx.x & 7 (one A-panel per XCD, L2-resident).
// LDS: A2 32KB + B2 44KB = 77.8KB -> 2 blocks/CU.
__global__ __launch_bounds__(256, 2) void conv_mfma(
    const ushort* __restrict__ Ag,
    const uint* __restrict__ d2hl,
    const float* __restrict__ pn, const float* __restrict__ wnorm,
    float* __restrict__ out)
{
    __shared__ __align__(16) ushort A2[2][2][4096];   // [buf][hl][128*32]
    __shared__ __align__(16) ushort B2[2][2][5632];   // [buf][hl][128*44]

    const int t = threadIdx.x;
    const int mb = blockIdx.x & 7;        // XCD-pinned M-panel
    const int nb = blockIdx.x >> 3;       // 0..152
    const int ny0 = (nb / 9) * 8;
    const int nx0 = (nb % 9) * 16;
    const int p0 = mb * 128;

    const int l = t & 63;
    const int w = t >> 6;
    const int wm = w & 1, wn_ = w >> 1;
    const int lm = l & 15, lg = l >> 4;

    // B staging mapping: m4 = channel quad, chunk -> (sny, snx4)
    const int m4 = t & 7;
    const int chunk = t >> 3;
    const int sny = chunk >> 2;
    const int snx4 = (chunk & 3) * 4;
    const int nrow0 = sny * 16 + snx4;

    f32x4 accH[4][4] = {};
    f32x4 accX[4][4] = {};

    uint4 Wb[4];

    auto stageA = [&](int s, int cur) {
        const ushort* src = Ag + (long)(mb * 64 + s) * 8192;
        ushort* dst = &A2[cur][0][0];
        #pragma unroll
        for (int i = 0; i < 4; ++i)
            gld_lds16(src + (i * 256 + t) * 8, dst + (i * 256 + t) * 8);
    };
    auto loadB = [&](int s) {
        int ab = s >> 2;
        int a = ab >> 2, b = ab & 3, c0 = (s & 3) * 32;
        int c = c0 + 4 * m4;
        int yy2 = ny0 + sny + a;                      // padded y index
        int xp0 = nx0 + snx4 + b;                     // padded x index of xi=0
        long base = ((long)c * 140 + yy2) * 152 + xp0;
        #pragma unroll
        for (int cc = 0; cc < 4; ++cc)
            Wb[cc] = *(const uint4*)(d2hl + base + cc * 21280);
    };
    auto writeB = [&](int cur) {
        #pragma unroll
        for (int xi = 0; xi < 4; ++xi) {
            uint w0, w1, w2, w3;
            if (xi == 0)      { w0 = Wb[0].x; w1 = Wb[1].x; w2 = Wb[2].x; w3 = Wb[3].x; }
            else if (xi == 1) { w0 = Wb[0].y; w1 = Wb[1].y; w2 = Wb[2].y; w3 = Wb[3].y; }
            else if (xi == 2) { w0 = Wb[0].z; w1 = Wb[1].z; w2 = Wb[2].z; w3 = Wb[3].z; }
            else              { w0 = Wb[0].w; w1 = Wb[1].w; w2 = Wb[2].w; w3 = Wb[3].w; }
            uint2 vh, vl;
            vh.x = __builtin_amdgcn_perm(w1, w0, 0x05040100u);  // {h0,h1}
            vh.y = __builtin_amdgcn_perm(w3, w2, 0x05040100u);  // {h2,h3}
            vl.x = __builtin_amdgcn_perm(w1, w0, 0x07060302u);  // {l0,l1}
            vl.y = __builtin_amdgcn_perm(w3, w2, 0x07060302u);  // {l2,l3}
            int ro = (nrow0 + xi) * 44 + 4 * m4;
            *(uint2*)(&B2[cur][0][0] + ro) = vh;
            *(uint2*)(&B2[cur][1][0] + ro) = vl;
        }
    };

    // prologue: stage step 0
    stageA(0, 0);
    loadB(0);
    writeB(0);
    __syncthreads();   // drains vmcnt(0): A DMA complete; lgkm: B writes visible

    for (int s = 0; s < 64; ++s) {
        const int cur = s & 1;
        if (s < 63) { stageA(s + 1, cur ^ 1); loadB(s + 1); }  // overlap with MFMA

        f16x8 fah[4], fal[4];
        #pragma unroll
        for (int mi = 0; mi < 4; ++mi) {
            int ra = (wm * 64 + mi * 16 + lm) * 32 + lg * 8;
            fah[mi] = *(const f16x8*)(&A2[cur][0][0] + ra);
            fal[mi] = *(const f16x8*)(&A2[cur][1][0] + ra);
        }
        #pragma unroll
        for (int ni = 0; ni < 4; ++ni) {
            int rb = (wn_ * 64 + ni * 16 + lm) * 44 + lg * 8;
            f16x4 bh0 = *(const f16x4*)(&B2[cur][0][0] + rb);
            f16x4 bh1 = *(const f16x4*)(&B2[cur][0][0] + rb + 4);
            f16x4 bl0 = *(const f16x4*)(&B2[cur][1][0] + rb);
            f16x4 bl1 = *(const f16x4*)(&B2[cur][1][0] + rb + 4);
            f16x8 fbh = __builtin_shufflevector(bh0, bh1, 0, 1, 2, 3, 4, 5, 6, 7);
            f16x8 fbl = __builtin_shufflevector(bl0, bl1, 0, 1, 2, 3, 4, 5, 6, 7);
            #pragma unroll
            for (int mi = 0; mi < 4; ++mi) {
                accH[mi][ni] = __builtin_amdgcn_mfma_f32_16x16x32_f16(fah[mi], fbh, accH[mi][ni], 0, 0, 0);
                accX[mi][ni] = __builtin_amdgcn_mfma_f32_16x16x32_f16(fah[mi], fbl, accX[mi][ni], 0, 0, 0);
                accX[mi][ni] = __builtin_amdgcn_mfma_f32_16x16x32_f16(fal[mi], fbh, accX[mi][ni], 0, 0, 0);
            }
        }
        __syncthreads();            // reads of cur done (also drains vmcnt: DMA into cur^1 done)
        if (s < 63) writeB(cur ^ 1);
        __syncthreads();            // staging visible
    }

    // epilogue: combine, normalize, activate, store
    #pragma unroll
    for (int mi = 0; mi < 4; ++mi) {
        #pragma unroll
        for (int ni = 0; ni < 4; ++ni) {
            int y = ny0 + wn_ * 4 + ni;
            int x = nx0 + lm;
            if (y < HO && x < HO) {
                float wv = wnorm[y * HO + x];
                f32x4 vh = accH[mi][ni];
                f32x4 vx = accX[mi][ni];
                #pragma unroll
                for (int r = 0; r < 4; ++r) {
                    int p = p0 + wm * 64 + mi * 16 + lg * 4 + r;
                    float num = vh[r] + vx[r] * (1.0f / 2048.0f);
                    float c = num / (pn[p] * wv + EPSF);
                    out[(long)p * (HO * HO) + y * HO + x] = activate(c);
                }
            }
        }
    }
}

// ---------------- 3x3 stride-2 pad-1 maxpool ----------------
__global__ void maxpool_k(const float* __restrict__ in, float* __restrict__ out,
                          int GG, int h, int hp) {
    int idx = blockIdx.x * 256 + threadIdx.x;
    int tot = GG * hp * hp;
    if (idx >= tot) return;
    int s = idx % hp;
    int r = (idx / hp) % hp;
    int g = idx / (hp * hp);
    const float* base = in + (long)g * h * h;
    int y0 = 2 * r - 1, x0 = 2 * s - 1;
    float m = -1e30f;
    #pragma unroll
    for (int dy = 0; dy < 3; ++dy) {
        int y = y0 + dy;
        if ((unsigned)y >= (unsigned)h) continue;
        #pragma unroll
        for (int dx = 0; dx < 3; ++dx) {
            int x = x0 + dx;
            if ((unsigned)x >= (unsigned)h) continue;
            m = fmaxf(m, base[y * h + x]);
        }
    }
    out[idx] = m;
}

// ---------------- sparse_conv_fwd (weights==1, den==4) + activation ----------------
__global__ void sparse_fwd_k(const float* __restrict__ pooled, float* __restrict__ out,
                             int G2, int h) {
    int idx = blockIdx.x * 256 + threadIdx.x;
    int tot = G2 * G2 * h * h;
    if (idx >= tot) return;
    int x = idx % h;
    int y = (idx / h) % h;
    int J = (idx / (h * h)) % G2;
    int I = idx / (h * h * G2);
    int G = 2 * G2;
    float s = 0.f;
    #pragma unroll
    for (int di = 0; di < 2; ++di) {
        int yy = y + 1 - 2 * di;
        if ((unsigned)yy >= (unsigned)h) continue;
        #pragma unroll
        for (int dj = 0; dj < 2; ++dj) {
            int xx = x + 1 - 2 * dj;
            if ((unsigned)xx >= (unsigned)h) continue;
            s += pooled[((((2 * I + di) * G) + (2 * J + dj)) * (long)h + yy) * h + xx];
        }
    }
    out[idx] = activate(0.25f * s);
}

// ---------------- backward max_unpool (in place on lo) ----------------
__global__ void unpool_k(float* __restrict__ lo, const float* __restrict__ pooled,
                         const float* __restrict__ up, int G, int hl, int hp) {
    int idx = blockIdx.x * 256 + threadIdx.x;
    int tot = G * G * hl * hl;
    if (idx >= tot) return;
    int x = idx % hl;
    int y = (idx / hl) % hl;
    int gj = (idx / (hl * hl)) % G;
    int gi = idx / (hl * hl * G);
    float l = lo[idx];
    float m = pooled[(((long)gi * G + gj) * hp + (y >> 1)) * hp + (x >> 1)];
    if (l == m) {
        int ry = (y >> 1) - 1 + 2 * (gi & 1);
        int rx = (x >> 1) - 1 + 2 * (gj & 1);
        float uv = 0.f;
        if ((unsigned)ry < (unsigned)hp && (unsigned)rx < (unsigned)hp)
            uv = up[((((long)(gi >> 1)) * (G >> 1) + (gj >> 1)) * hp + ry) * hp + rx];
        lo[idx] = fmaxf(l, uv);
    }
}

// ---------------- workspace layout (float/uint units) ----------------
// d2hl: 128*140*152 = 2,723,840 uints
// Ag:   8*64*2*128*32 = 4,194,304 ushorts = 2,097,152 floats
#define PN_OFF    0L
#define WN_OFF    1024L                    // 16,641 -> ends 17,665
#define SQ_OFF    17728L                   // 16,384 -> ends 34,112
#define CBASE     34112L
#define D2HL_OFF  (CBASE)                  // [CBASE, CBASE+2,723,840)
#define AG_OFF    (CBASE + 2723840L)       // [.., CBASE+4,820,992)
// pyramid phase (aliases conv-phase buffers; disjoint in time):
#define POOL1_OFF (CBASE)                  // 4,326,400
#define PYR1_OFF  (CBASE + 4326400L)       // 1,081,600
#define POOL2_OFF (CBASE + 5408000L)       // 278,784
#define PYR2_OFF  (CBASE + 5686784L)       // 69,696
#define POOL3_OFF (CBASE + 5756480L)       // 18,496
#define PYR3_OFF  (CBASE + 5774976L)       // 4,624
#define POOL4_OFF (CBASE + 5779600L)       // 1,296
#define PYR4_OFF  (CBASE + 5780896L)       // 324
#define POOL5_OFF (CBASE + 5781220L)       // 100
#define PYR5_OFF  (CBASE + 5781320L)       // 25

extern "C" void kernel_launch(void* const* d_in, const int* in_sizes, int n_in,
                              void* d_out, int out_size, void* d_ws, size_t ws_size,
                              hipStream_t stream) {
    const float* d1 = (const float*)d_in[0];
    const float* d2 = (const float*)d_in[1];
    float* out = (float*)d_out;
    float* ws = (float*)d_ws;

    float* pnf   = ws + PN_OFF;
    float* wnf   = ws + WN_OFF;
    float* sqf   = ws + SQ_OFF;
    uint*  d2hl  = (uint*)(ws + D2HL_OFF);
    ushort* Ag   = (ushort*)(ws + AG_OFF);
    float* pool1 = ws + POOL1_OFF;
    float* pyr1  = ws + PYR1_OFF;
    float* pool2 = ws + POOL2_OFF;
    float* pyr2  = ws + PYR2_OFF;
    float* pool3 = ws + POOL3_OFF;
    float* pyr3  = ws + PYR3_OFF;
    float* pool4 = ws + POOL4_OFF;
    float* pyr4  = ws + PYR4_OFF;
    float* pool5 = ws + POOL5_OFF;
    float* pyr5  = ws + PYR5_OFF;

    // prep
    split_d2<<<10640, 256, 0, stream>>>(d2, d2hl);
    build_Afrag<<<8192, 256, 0, stream>>>(d1, Ag);
    pnorm_k<<<1024, 64, 0, stream>>>(d1, pnf);
    sq_k<<<64, 256, 0, stream>>>(d2, sqf);
    wnorm_k<<<(HO * HO + 255) / 256, 256, 0, stream>>>(sqf, wnf);

    // correlation GEMM (MFMA) + normalize + activation -> pyramid0 in d_out
    conv_mfma<<<8 * 153, 256, 0, stream>>>(Ag, d2hl, pnf, wnf, out);

    // forward pyramid (cache pooled at every level)
    maxpool_k<<<(1024 * 65 * 65 + 255) / 256, 256, 0, stream>>>(out, pool1, 1024, 129, 65);
    sparse_fwd_k<<<(256 * 65 * 65 + 255) / 256, 256, 0, stream>>>(pool1, pyr1, 16, 65);

    maxpool_k<<<(256 * 33 * 33 + 255) / 256, 256, 0, stream>>>(pyr1, pool2, 256, 65, 33);
    sparse_fwd_k<<<(64 * 33 * 33 + 255) / 256, 256, 0, stream>>>(pool2, pyr2, 8, 33);

    maxpool_k<<<(64 * 17 * 17 + 255) / 256, 256, 0, stream>>>(pyr2, pool3, 64, 33, 17);
    sparse_fwd_k<<<(16 * 17 * 17 + 255) / 256, 256, 0, stream>>>(pool3, pyr3, 4, 17);

    maxpool_k<<<(16 * 9 * 9 + 255) / 256, 256, 0, stream>>>(pyr3, pool4, 16, 17, 9);
    sparse_fwd_k<<<(4 * 9 * 9 + 255) / 256, 256, 0, stream>>>(pool4, pyr4, 2, 9);

    maxpool_k<<<1, 256, 0, stream>>>(pyr4, pool5, 4, 9, 5);
    sparse_fwd_k<<<1, 256, 0, stream>>>(pool5, pyr5, 1, 5);

    // backward unpool chain (top -> bottom), each updates lo in place
    unpool_k<<<(4 * 81 + 255) / 256, 256, 0, stream>>>(pyr4, pool5, pyr5, 2, 9, 5);
    unpool_k<<<(16 * 289 + 255) / 256, 256, 0, stream>>>(pyr3, pool4, pyr4, 4, 17, 9);
    unpool_k<<<(64 * 1089 + 255) / 256, 256, 0, stream>>>(pyr2, pool3, pyr3, 8, 33, 17);
    unpool_k<<<(256 * 4225 + 255) / 256, 256, 0, stream>>>(pyr1, pool2, pyr2, 16, 65, 33);
    unpool_k<<<(1024 * 16641 + 255) / 256, 256, 0, stream>>>(out, pool1, pyr1, 32, 129, 65);
}